// Round 9
// baseline (253.527 us; speedup 1.0000x reference)
//
#include <hip/hip_runtime.h>
#include <hip/hip_fp16.h>

// Problem constants (from reference):
//   x:    (B=2, C=8, F=80, N=128, N=128) fp32
//   quad: (H=512, W=1024) int32 in [0, F)
//   uv:   (H, W, 2) fp32 in [0, N-1)
//   out:  (B, C, H, W) fp32
#define BC   16                 // B*C
#define FD   80
#define ND   128
#define NN   (ND * ND)          // 16384
#define HW   (512 * 1024)       // 524288 = 2^19
#define HW_SHIFT 19

#define YH_BYTES ((size_t)FD * NN * BC * sizeof(__half))   // 41,943,040

// Native clang vector type — legal for __builtin_nontemporal_load/store.
typedef unsigned int v4u __attribute__((ext_vector_type(4)));

// ---------------------------------------------------------------------------
// Kernel 1 (repack v5): x[bc][f][v][u] fp32 -> y[f][v][u][bc] fp16.
// One thread per 4 texels: 16 float4 loads (1 KB/wave-instr, coalesced),
// register transpose, 8 contiguous 16B nontemporal stores (write-only
// stream; L2 flushes at kernel end, so caching y here can't help gather).
// No LDS, no barrier, no bank conflicts.
// ---------------------------------------------------------------------------
__global__ __launch_bounds__(256)
void repack_kernel(const float* __restrict__ x, __half* __restrict__ y)
{
    const int t  = blockIdx.x * 256 + threadIdx.x;   // 0 .. FD*ND*ND/4 - 1
    const int u4 = t & 31;                           // float4 index along u
    const int fv = t >> 5;                           // f*128 + v
    const int f  = fv >> 7;
    const int v  = fv & (ND - 1);

    // 16 coalesced float4 loads (within-wave lanes are consecutive u4
    // -> 1 KB contiguous per instruction).
    float4 g[BC];
#pragma unroll
    for (int c = 0; c < BC; ++c)
        g[c] = *(const float4*)(x + (((size_t)c * FD + f) * ND + v) * ND + u4 * 4);

    // Transpose in registers: 4 texels x 16 channels, pack to fp16.
    __half* yp = y + ((size_t)fv * ND + (size_t)u4 * 4) * BC;
#pragma unroll
    for (int k = 0; k < 4; ++k) {
        unsigned hp[8];
#pragma unroll
        for (int j = 0; j < 8; ++j) {
            const float a = ((const float*)&g[2 * j    ])[k];
            const float b = ((const float*)&g[2 * j + 1])[k];
            const __half2 h = __floats2half2_rn(a, b);
            hp[j] = *(const unsigned*)&h;
        }
        const v4u lo = { hp[0], hp[1], hp[2], hp[3] };
        const v4u hi = { hp[4], hp[5], hp[6], hp[7] };
        __builtin_nontemporal_store(lo, (v4u*)(yp + k * BC));
        __builtin_nontemporal_store(hi, (v4u*)(yp + k * BC + 8));
    }
}

// ---------------------------------------------------------------------------
// Kernel 2 (gather v5): ONE thread per pixel, all 16 channels.
// 8 CACHED 16B texel loads (the ~1.6x line reuse across pixels hits L2/L3;
// round-8 nt loads lost it: FETCH 122 MB vs ~90 structural-with-reuse).
// 2048 blocks -> 32 waves/CU for latency hiding. nt stores only for out.
// ---------------------------------------------------------------------------
__device__ inline void acc8(float* o, v4u t, float w)
{
#pragma unroll
    for (int j = 0; j < 4; ++j) {
        const unsigned w32 = t[j];
        const float2 fp = __half22float2(*(const __half2*)&w32);
        o[2 * j + 0] += fp.x * w;
        o[2 * j + 1] += fp.y * w;
    }
}

__global__ __launch_bounds__(256)
void gather_kernel(const __half* __restrict__ y,
                   const int*    __restrict__ quad,
                   const float2* __restrict__ uv2,
                   float* __restrict__ out)
{
    const int pix = blockIdx.x * 256 + threadIdx.x;

    const float2 t = uv2[pix];
    const int    f = quad[pix];

    const float u = t.x;
    const float v = t.y;

    int u0 = (int)floorf(u);
    int v0 = (int)floorf(v);
    u0 = min(max(u0, 0), ND - 2);
    v0 = min(max(v0, 0), ND - 2);

    // Issue all 8 texel loads (128 B, all consumed) before the weight math.
    const size_t base = (((size_t)f * ND + v0) * ND + u0) * BC;
    const v4u* r0 = (const v4u*)(y + base);                    // (v0,  u0..u0+1)
    const v4u* r1 = (const v4u*)(y + base + (size_t)ND * BC);  // (v0+1,u0..u0+1)
    const v4u a0 = r0[0], a1 = r0[1];   // (v0,u0)   ch0-7, ch8-15
    const v4u b0 = r0[2], b1 = r0[3];   // (v0,u0+1)
    const v4u c0 = r1[0], c1 = r1[1];   // (v1,u0)
    const v4u d0 = r1[2], d1 = r1[3];   // (v1,u0+1)

    const float du = u - (float)u0;
    const float dv = v - (float)v0;
    const float w00 = (1.0f - du) * (1.0f - dv);
    const float w01 = du * (1.0f - dv);
    const float w10 = (1.0f - du) * dv;
    const float w11 = du * dv;

    float o[BC];
#pragma unroll
    for (int c = 0; c < BC; ++c) o[c] = 0.0f;

    acc8(o,     a0, w00); acc8(o + 8, a1, w00);
    acc8(o,     b0, w01); acc8(o + 8, b1, w01);
    acc8(o,     c0, w10); acc8(o + 8, c1, w10);
    acc8(o,     d0, w11); acc8(o + 8, d1, w11);

    // 16 coalesced nontemporal scalar stores (256 B per wave per plane).
#pragma unroll
    for (int c = 0; c < BC; ++c)
        __builtin_nontemporal_store(o[c], &out[(size_t)c * HW + pix]);
}

// ---------------------------------------------------------------------------
// Fallback: used only if ws_size can't hold the repacked texture.
// ---------------------------------------------------------------------------
__global__ __launch_bounds__(256)
void resample_fallback_kernel(const float* __restrict__ x,
                              const int*   __restrict__ quad,
                              const float2* __restrict__ uv2,
                              float* __restrict__ out)
{
    const int gid = blockIdx.x * 256 + threadIdx.x;
    const int pix = gid & (HW - 1);
    const int bc  = gid >> HW_SHIFT;

    const float2 t = uv2[pix];
    const int    f = quad[pix];

    const float u = t.x;
    const float v = t.y;

    int u0 = (int)floorf(u);
    int v0 = (int)floorf(v);
    u0 = min(max(u0, 0), ND - 2);
    v0 = min(max(v0, 0), ND - 2);

    const float du = u - (float)u0;
    const float dv = v - (float)v0;

    const float w00 = (1.0f - du) * (1.0f - dv);
    const float w01 = du * (1.0f - dv);
    const float w10 = (1.0f - du) * dv;
    const float w11 = du * dv;

    const float* p = x + ((size_t)bc * FD + (size_t)f) * NN + v0 * ND + u0;
    out[gid] = p[0] * w00 + p[1] * w01 + p[ND] * w10 + p[ND + 1] * w11;
}

extern "C" void kernel_launch(void* const* d_in, const int* in_sizes, int n_in,
                              void* d_out, int out_size, void* d_ws, size_t ws_size,
                              hipStream_t stream)
{
    const float*  x    = (const float*)d_in[0];
    const int*    quad = (const int*)d_in[1];
    const float2* uv2  = (const float2*)d_in[2];
    float*        out  = (float*)d_out;

    if (ws_size >= YH_BYTES) {
        __half* y = (__half*)d_ws;
        const int rp_threads = FD * ND * ND / 4;                 // 327,680
        repack_kernel<<<rp_threads / 256, 256, 0, stream>>>(x, y);       // 1280 blocks
        gather_kernel<<<HW / 256, 256, 0, stream>>>(y, quad, uv2, out);  // 2048 blocks
    } else {
        const int total = BC * HW;
        resample_fallback_kernel<<<total / 256, 256, 0, stream>>>(x, quad, uv2, out);
    }
}